// Round 11
// baseline (119.174 us; speedup 1.0000x reference)
//
#include <hip/hip_runtime.h>
#include <math.h>

#define B_ 16
#define L_ 128
#define D_ 768
#define H1_ 770
#define OUT_ 40
#define NPAIRS 3405     // sum over i of min(30, 128-i)
#define NLOG 1540       // logical cols of Y: U(770) || V(770)
#define YSB 1552        // bf16 Y row stride in shorts (16B-aligned rows)
#define VOFFB 776       // V part at +776 shorts (1552 B, 16B-aligned)
#define KPAD 800        // 25 x 32 MFMA k-steps (k >= 770 zero-padded in B/Cv)
#define W1TROWS 1600    // W1T rows padded (zeros in [1540,1600)) for safe staging
#define NKS 25
#define NTILES 252      // 4x4 (i,j) tiles covering the band
#define BSWZ_N (26 * 3 * 512)   // 25 real k-steps + 1 zero step (prefetch pad)

// virtual block ranges
#define NB_X 1536      // X convert: 2048*192 vec4-units / 256
#define NB_W 166       // Bswz (26*3*512) + Cv (3*800), ceil(42336/256)
#define NB_T 1200      // W1T transpose: 50 n-tiles x 24 k-tiles
#define NB_A (NB_X + NB_W + NB_T)
#define NB_B 800       // gemm tiles 25 cols x 32 row-panels
#define NB_C (NTILES * 16)   // pair: 252 tiles x 16 batches, 1 wave each

typedef __attribute__((ext_vector_type(8))) short bf16x8;
typedef __attribute__((ext_vector_type(8))) unsigned short u16x8;
typedef __attribute__((ext_vector_type(4))) float f32x4;
typedef __attribute__((ext_vector_type(4))) unsigned int u32x4;

__device__ inline unsigned short f2bf(float f) {
  unsigned int u = __builtin_bit_cast(unsigned int, f);
  u += 0x7fffu + ((u >> 16) & 1u);          // round-to-nearest-even
  return (unsigned short)(u >> 16);
}

#if __has_builtin(__builtin_amdgcn_cvt_pk_bf16_f32)
typedef __attribute__((ext_vector_type(2))) __bf16 bf16x2_t;
__device__ inline unsigned int pack_bf16(float lo, float hi) {
  bf16x2_t r = __builtin_amdgcn_cvt_pk_bf16_f32(lo, hi);
  return __builtin_bit_cast(unsigned int, r);
}
#else
__device__ inline unsigned int pack_bf16(float lo, float hi) {
  return (unsigned int)f2bf(lo) | ((unsigned int)f2bf(hi) << 16);
}
#endif

// async global->LDS, 16B per lane; LDS dest = wave-uniform base + lane*16
typedef const __attribute__((address_space(1))) void* gas_t;
typedef __attribute__((address_space(3))) void* las_t;
__device__ inline void gl2lds16(const void* g, void* l) {
  __builtin_amdgcn_global_load_lds((gas_t)g, (las_t)l, 16, 0, 0);
}

// tile decode: T -> (ti, d); tile = i in [4ti,4ti+4) x j in [4(ti+d),+4)
__device__ inline void tile_decode(int T, int& ti, int& d) {
  if (T < 216) { ti = T / 9; d = T - ti * 9; }
  else {
    int m = T - 216; int r = 24, w = 8;
    while (m >= w) { m -= w; --w; ++r; }
    ti = r; d = m;
  }
}
// row-major rank of an in-band pair (i,j)
__device__ inline int pair_rank(int i, int j) {
  return (i < 99) ? i * 30 + (j - i)
                  : NPAIRS - (128 - i) * (129 - i) / 2 + (j - i);
}

// ---------------------------------------------------------------------------
// Kernel A: prep (X bf16 convert | Bswz/Cv | W1T transpose)
// Cv = ind*w1c only (b1 folded into gemm epilogue), stored even/odd-split
// within each 8-group: [g*8+0..3] = k = g*8+{0,2,4,6}; [g*8+4..7] = {1,3,5,7}.
// ---------------------------------------------------------------------------
__global__ __launch_bounds__(256) void prep_k(
    const float* __restrict__ hidden, const float* __restrict__ W1,
    const float* __restrict__ b1, const float* __restrict__ W2,
    unsigned short* __restrict__ Xb, unsigned short* __restrict__ W1T,
    unsigned short* __restrict__ Bswz, float* __restrict__ Cv)
{
  __shared__ float t[32][33];
  const int u = blockIdx.x;
  const int tid = threadIdx.x;

  if (u < NB_X) {                        // ---- X convert ----
    int idx = u * 256 + tid;
    int m = idx / 192;
    int c = idx - m * 192;
    float4 f = *(const float4*)(hidden + (size_t)(m + (m >> 7) + 1) * D_ + c * 4);
    ushort4 o;
    o.x = f2bf(f.x); o.y = f2bf(f.y); o.z = f2bf(f.z); o.w = f2bf(f.w);
    *(ushort4*)(Xb + (size_t)m * D_ + c * 4) = o;
  } else if (u < NB_X + NB_W) {          // ---- Bswz + Cv ----
    int idx = (u - NB_X) * 256 + tid;
    if (idx < BSWZ_N) {                  // ks=25 block is all zeros (pad)
      int ks = idx / 1536;
      int rem = idx - ks * 1536;
      int f = rem / 512;
      int l = (rem - f * 512) >> 3;
      int e = rem & 7;
      int n = f * 16 + (l & 15);
      int k = ks * 32 + (l >> 4) * 8 + e;
      float v = (n < OUT_ && k < H1_) ? W2[k * OUT_ + n] : 0.f;
      Bswz[idx] = f2bf(v);
    } else if (idx < BSWZ_N + 3 * KPAD) {
      int c = idx - BSWZ_N;
      int tt = c / KPAD, rem = c - tt * KPAD;
      int g = rem >> 3, pos = rem & 7;
      int m = (pos < 4) ? (pos * 2) : ((pos - 4) * 2 + 1);
      int k = g * 8 + m;
      const float* w1c = W1 + 1536 * H1_;
      Cv[c] = (k < H1_) ? ((float)tt * w1c[k]) : 0.f;   // Cv[0] is all zeros
    }
  } else {                               // ---- W1T transpose ----
    int bx = u - NB_X - NB_W;
    const int tx = tid & 31, ty = tid >> 5;
    const int n0 = (bx % 50) * 32, k0 = (bx / 50) * 32;
    #pragma unroll
    for (int r = 0; r < 4; ++r) {
      int k = k0 + ty + r * 8, n = n0 + tx;
      float v = 0.f;
      if (n < H1_)       v = W1[k * H1_ + n];
      else if (n < NLOG) v = W1[(D_ + k) * H1_ + (n - H1_)];
      t[ty + r * 8][tx] = v;
    }
    __syncthreads();
    #pragma unroll
    for (int r = 0; r < 4; ++r) {
      int n = n0 + ty + r * 8, k = k0 + tx;
      W1T[(size_t)n * D_ + k] = f2bf(t[tx][ty + r * 8]);   // n < 1600 always
    }
  }
}

// ---------------------------------------------------------------------------
// Kernel B: Yb = Xb @ W1T^T (bf16), 64x64 tile, BK=128 (6 two-barrier iters),
// global_load_lds, 16-chunk XOR swizzle (uniform 8 dwords/bank — conflict-
// free for both staging and b128 frag reads), XCD panel swizzle, b1 folded
// into the U-part epilogue.
// ---------------------------------------------------------------------------
__global__ __launch_bounds__(256) void gemm_k(
    const unsigned short* __restrict__ Xb, const unsigned short* __restrict__ W1T,
    const float* __restrict__ b1, unsigned short* __restrict__ Yb)
{
  __shared__ unsigned short As[64][128];   // 16 KB
  __shared__ unsigned short Bs[64][128];   // 16 KB
  const int tid = threadIdx.x;
  const int lane = tid & 63, w = tid >> 6;
  const int lm = lane & 15, q = lane >> 4;
  const int xcd = blockIdx.x & 7;
  const int t = blockIdx.x >> 3;                 // 0..99
  const int col0 = (t % 25) * 64;
  const int row0 = (xcd * 4 + t / 25) * 64;      // all 32 panels covered
  const int m0 = (w >> 1) * 32, n0 = (w & 1) * 32;

  // staging: wave w owns rows [w*16,+16); instr i covers rows +4i..+4i+3;
  // lane l -> row +4i+(l>>4), physical slot l&15 holds global chunk
  // (l&15)^(row&15). Pointers are k0-invariant: precompute.
  const unsigned short* ga4[4];
  const unsigned short* gb4[4];
  #pragma unroll
  for (int i = 0; i < 4; ++i) {
    int srow = w * 16 + 4 * i + (lane >> 4);
    int chunk = (lane & 15) ^ (srow & 15);
    ga4[i] = Xb  + (size_t)(row0 + srow) * D_ + chunk * 8;
    gb4[i] = W1T + (size_t)(col0 + srow) * D_ + chunk * 8;
  }

  f32x4 acc[2][2] = {};

  for (int k0 = 0; k0 < D_; k0 += 128) {
    #pragma unroll
    for (int i = 0; i < 4; ++i) {
      gl2lds16(ga4[i] + k0, &As[w * 16 + 4 * i][0]);
      gl2lds16(gb4[i] + k0, &Bs[w * 16 + 4 * i][0]);
    }
    __syncthreads();
    #pragma unroll
    for (int ks = 0; ks < 4; ++ks) {
      const int cc = (((ks * 4 + q) ^ lm)) * 8;   // reader xor key = row&15 = lm
      bf16x8 a0 = *(const bf16x8*)&As[m0 + lm]     [cc];
      bf16x8 a1 = *(const bf16x8*)&As[m0 + 16 + lm][cc];
      bf16x8 b0 = *(const bf16x8*)&Bs[n0 + lm]     [cc];
      bf16x8 b1v = *(const bf16x8*)&Bs[n0 + 16 + lm][cc];
      acc[0][0] = __builtin_amdgcn_mfma_f32_16x16x32_bf16(a0, b0, acc[0][0], 0, 0, 0);
      acc[0][1] = __builtin_amdgcn_mfma_f32_16x16x32_bf16(a0, b1v, acc[0][1], 0, 0, 0);
      acc[1][0] = __builtin_amdgcn_mfma_f32_16x16x32_bf16(a1, b0, acc[1][0], 0, 0, 0);
      acc[1][1] = __builtin_amdgcn_mfma_f32_16x16x32_bf16(a1, b1v, acc[1][1], 0, 0, 0);
    }
    __syncthreads();
  }

  // epilogue: C/D layout col=lane&15, row=q*4+r; +b1 on U-part; store bf16
  #pragma unroll
  for (int tj = 0; tj < 2; ++tj) {
    int col = col0 + n0 + tj * 16 + lm;
    if (col >= NLOG) continue;
    float badd = (col < H1_) ? b1[col] : 0.f;
    int pc = (col < H1_) ? col : col + (VOFFB - H1_);
    #pragma unroll
    for (int ti = 0; ti < 2; ++ti) {
      #pragma unroll
      for (int r = 0; r < 4; ++r) {
        int row = row0 + m0 + ti * 16 + q * 4 + r;
        Yb[(size_t)row * YSB + pc] = f2bf(acc[ti][tj][r] + badd);
      }
    }
  }
}

// ---------------------------------------------------------------------------
// Kernel C: pair — one wave per block, 252 tiles x 16 batches, XCD-local
// batches (bb = u&15). Packed-f32 h pipeline (v_pk_add/max), per-wave ballot
// skips the indicator term for tiles outside the span box (~89% of waves).
// U/V prefetch depth 2, B rotation depth 1 (zero-padded 26th k-step).
// ---------------------------------------------------------------------------
__global__ __launch_bounds__(64) void pair_k(
    const unsigned short* __restrict__ Yb, const int* __restrict__ spans,
    const unsigned short* __restrict__ Bswz, const float* __restrict__ Cv,
    const float* __restrict__ b2, float* __restrict__ out)
{
  const int tid = threadIdx.x;           // 0..63
  const int u = blockIdx.x;
  const int bb = u & 15;
  const int T = u >> 4;                  // 0..251
  const int lm = tid & 15, q = tid >> 4;

  int ti, d;
  tile_decode(T, ti, d);
  const int i0 = ti * 4, j0 = (ti + d) * 4;

  const int ai = i0 + (lm & 3);
  const int aj = j0 + (lm >> 2);
  const int s = spans[2 * bb], e = spans[2 * bb + 1];
  const int ind = (ai == s && aj == e) ? 2 : ((ai >= s && aj <= e) ? 1 : 0);
  const bool withc = (__ballot(ind != 0) != 0ull);   // wave-uniform

  const unsigned short* uptr = Yb + (size_t)(bb * L_ + ai) * YSB + q * 8;
  const unsigned short* vptr = Yb + (size_t)(bb * L_ + aj) * YSB + VOFFB + q * 8;
  const float* cptr = Cv + ind * KPAD + q * 8;
  const unsigned short* bbase = Bswz + tid * 8;

  f32x4 acc0 = {}, acc1 = {}, acc2 = {};
  const f32x4 zero = {0.f, 0.f, 0.f, 0.f};

  auto run = [&](bool usec) {
    // pipeline primes: U/V depth 2, B depth 1
    u16x8 uu0 = *(const u16x8*)(uptr);
    u16x8 vv0 = *(const u16x8*)(vptr);
    u16x8 uu1 = *(const u16x8*)(uptr + 32);
    u16x8 vv1 = *(const u16x8*)(vptr + 32);
    bf16x8 nb0 = *(const bf16x8*)(bbase + 0 * 512);
    bf16x8 nb1 = *(const bf16x8*)(bbase + 1 * 512);
    bf16x8 nb2 = *(const bf16x8*)(bbase + 2 * 512);

    #pragma unroll 5
    for (int ks = 0; ks < NKS; ++ks) {
      const int ko = ks * 32;
      u16x8 cu = uu0, cw = vv0;
      uu0 = uu1; vv0 = vv1;
      uu1 = *(const u16x8*)(uptr + ko + 64);   // tail lands in spare row
      vv1 = *(const u16x8*)(vptr + ko + 64);
      bf16x8 b0 = nb0, b1v = nb1, b2f = nb2;
      nb0 = *(const bf16x8*)(bbase + (size_t)(ks * 3 + 3) * 512);
      nb1 = *(const bf16x8*)(bbase + (size_t)(ks * 3 + 4) * 512);
      nb2 = *(const bf16x8*)(bbase + (size_t)(ks * 3 + 5) * 512);

      // packed h: lo lane = elems {0,2,4,6}, hi = {1,3,5,7} (Cv pre-split)
      u32x4 ud = __builtin_bit_cast(u32x4, cu);
      u32x4 vd = __builtin_bit_cast(u32x4, cw);
      f32x4 slo = __builtin_bit_cast(f32x4, ud << 16)
                + __builtin_bit_cast(f32x4, vd << 16);
      f32x4 shi = __builtin_bit_cast(f32x4, ud & 0xffff0000u)
                + __builtin_bit_cast(f32x4, vd & 0xffff0000u);
      if (usec) {
        slo += *(const f32x4*)(cptr + ko);
        shi += *(const f32x4*)(cptr + ko + 4);
      }
      slo = __builtin_elementwise_max(slo, zero);
      shi = __builtin_elementwise_max(shi, zero);
      u32x4 hp;
      hp[0] = pack_bf16(slo[0], shi[0]);
      hp[1] = pack_bf16(slo[1], shi[1]);
      hp[2] = pack_bf16(slo[2], shi[2]);
      hp[3] = pack_bf16(slo[3], shi[3]);
      bf16x8 a = __builtin_bit_cast(bf16x8, hp);
      acc0 = __builtin_amdgcn_mfma_f32_16x16x32_bf16(a, b0, acc0, 0, 0, 0);
      acc1 = __builtin_amdgcn_mfma_f32_16x16x32_bf16(a, b1v, acc1, 0, 0, 0);
      acc2 = __builtin_amdgcn_mfma_f32_16x16x32_bf16(a, b2f, acc2, 0, 0, 0);
    }
  };
  if (withc) run(true); else run(false);

  // epilogue: C/D row p=4q+r -> pair (i0+r, j0+q), col lm.
  const float b2v0 = b2[lm];
  const float b2v1 = b2[16 + lm];
  const float b2v2 = (lm < 8) ? b2[32 + lm] : 0.f;

  #pragma unroll
  for (int r = 0; r < 4; ++r) {
    float l0 = acc0[r] + b2v0;
    float l1 = acc1[r] + b2v1;
    float l2 = (lm < 8) ? (acc2[r] + b2v2) : -INFINITY;
    float mx = fmaxf(fmaxf(l0, l1), l2);
    mx = fmaxf(mx, __shfl_xor(mx, 1));
    mx = fmaxf(mx, __shfl_xor(mx, 2));
    mx = fmaxf(mx, __shfl_xor(mx, 4));
    mx = fmaxf(mx, __shfl_xor(mx, 8));
    float sm = expf(l0 - mx) + expf(l1 - mx) + ((lm < 8) ? expf(l2 - mx) : 0.f);
    sm += __shfl_xor(sm, 1);
    sm += __shfl_xor(sm, 2);
    sm += __shfl_xor(sm, 4);
    sm += __shfl_xor(sm, 8);
    float lsd = mx + logf(sm);

    int pi_ = i0 + r, pj_ = j0 + q;
    if (pj_ >= pi_ && (pj_ - pi_) < 30) {
      float* op = out + ((size_t)bb * NPAIRS + pair_rank(pi_, pj_)) * OUT_;
      op[lm]      = l0 - lsd;
      op[16 + lm] = l1 - lsd;
      if (lm < 8) op[32 + lm] = l2 - lsd;
    }
  }
}

// ---------------------------------------------------------------------------
extern "C" void kernel_launch(void* const* d_in, const int* in_sizes, int n_in,
                              void* d_out, int out_size, void* d_ws, size_t ws_size,
                              hipStream_t stream) {
  const float* hidden = (const float*)d_in[0];   // (16,129,768) f32
  const int*   spans  = (const int*)d_in[1];     // (16,2) i32
  const float* W1 = (const float*)d_in[4];       // (1537,770) f32
  const float* b1 = (const float*)d_in[5];       // (770,)
  const float* W2 = (const float*)d_in[6];       // (770,40)
  const float* b2 = (const float*)d_in[7];       // (40,)
  float* out = (float*)d_out;                    // (16,3405,40) f32

  // workspace layout (256B-aligned slabs). Yb has one spare row: pair_k's
  // V prefetch on the last row overruns by <=112 shorts into poisoned-but-
  // finite space (multiplied by Bswz zero pad or never used).
  char* base = (char*)d_ws;
  size_t off = 0;
  auto take = [&](size_t bytes) {
    char* p = base + off;
    off = (off + bytes + 255) & ~(size_t)255;
    return p;
  };
  unsigned short* Yb   = (unsigned short*)take((size_t)2049 * YSB * 2);     // 6.36 MB
  unsigned short* Xb   = (unsigned short*)take((size_t)2048 * D_ * 2);      // 3.15 MB
  unsigned short* W1T  = (unsigned short*)take((size_t)W1TROWS * D_ * 2);   // 2.46 MB
  unsigned short* Bswz = (unsigned short*)take((size_t)BSWZ_N * 2);         // 79.9 KB
  float*          Cv   = (float*)take((size_t)3 * KPAD * 4);                // 9.6 KB

  prep_k<<<dim3(NB_A), 256, 0, stream>>>(hidden, W1, b1, W2, Xb, W1T, Bswz, Cv);
  gemm_k<<<dim3(NB_B), 256, 0, stream>>>(Xb, W1T, b1, Yb);
  pair_k<<<dim3(NB_C), 64, 0, stream>>>(Yb, spans, Bswz, Cv, b2, out);
}